// Round 8
// baseline (155.846 us; speedup 1.0000x reference)
//
#include <hip/hip_runtime.h>
#include <hip/hip_bf16.h>

#define NS 32768          // B*S samples
#define EMB 512
#define KDIM 2048
#define BM 256
#define BN 128
#define NITER (KDIM / 32)   // 64

typedef float f32x16 __attribute__((ext_vector_type(16)));
typedef __bf16 bf16x8 __attribute__((ext_vector_type(8)));
typedef __bf16 bf16x2 __attribute__((ext_vector_type(2)));
typedef unsigned int u32;

// pack two floats into one u32 of 2 bf16 (v_cvt_pk_bf16_f32), RNE
__device__ __forceinline__ u32 pk2(float lo, float hi) {
    union { bf16x2 h; u32 u; } c;
    c.h[0] = (__bf16)lo;
    c.h[1] = (__bf16)hi;
    return c.u;
}

// pack two relu'd floats into one u32 of 2 bf16
__device__ __forceinline__ u32 pkrelu(float lo, float hi) {
    union { bf16x2 h; u32 u; } c;
    c.h[0] = (__bf16)fmaxf(lo, 0.f);
    c.h[1] = (__bf16)fmaxf(hi, 0.f);
    return c.u;
}

__device__ __forceinline__ bf16x8 mk_af(u32 a, u32 b, u32 c, u32 d) {
    union { u32 u[4]; bf16x8 v; } t;
    t.u[0] = a; t.u[1] = b; t.u[2] = c; t.u[3] = d;
    return t.v;
}

// GEMM1 C/D regs -> two GEMM2 A-fragments. With the hidden-index
// pre-permutation (W1/b1 rows permuted by p(i) at stage time, verified r5-7),
// D reg r at (l31,half) holds H_orig[k0 + t*16 + half*8 + j] in A-frag
// order: af0 = regs 0..7 pairwise-packed, af1 = regs 8..15. No cross-lane.
__device__ __forceinline__ void h_to_af(const f32x16 h, bf16x8& af0, bf16x8& af1) {
    af0 = mk_af(pkrelu(h[0], h[1]),  pkrelu(h[2], h[3]),
                pkrelu(h[4], h[5]),  pkrelu(h[6], h[7]));
    af1 = mk_af(pkrelu(h[8], h[9]),  pkrelu(h[10], h[11]),
                pkrelu(h[12], h[13]), pkrelu(h[14], h[15]));
}

// ---- SINGLE fused kernel: no k_prep, no workspace. ----
// C[256,128-tile] = relu(ev @ W1^T + b1) @ W2^T + b2, all casts in-kernel.
//  * W1/b1 f32 -> bf16 (+ permutation p) during prologue LDS staging.
//  * W2 f32 staged per K-tile: reg-load (2x float4/frag) -> cvt_pk -> ds_write.
//    Pipeline per iter T: COMPUTE_AF(T) -> cvt+write tile T+1 (loads issued
//    at T-1; ~700cyc hiding) -> issue loads T+2 -> lgkmcnt(0) -> s_barrier
//    -> GEMM2(T). Loads stay in flight across the barrier.
//  * 4 LDS buffers: writer hits (T+1)&3; laggard readers (T-1)&3 -> disjoint.
//  * GEMM1 on MFMA pipe (b1 folded in k=8 slot), reuse-2 GEMM2, setprio.
__global__ __launch_bounds__(256, 2) void k_gemm(
        const float* __restrict__ x,       // [NS, 8]
        const float* __restrict__ params,  // [8, 3]
        const float* __restrict__ W1,      // [2048, 8] f32
        const float* __restrict__ b1,      // [2048]
        const float* __restrict__ W2,      // [512, 2048] f32
        const float* __restrict__ b2,      // [512]
        float* __restrict__ C) {           // [NS, 512]
    __shared__ __align__(16) __hip_bfloat16 Bs[4][8 * 512];  // 4 x 8 KB
    __shared__ __align__(16) __hip_bfloat16 W1s[KDIM * 8];   // 32 KB (perm p)
    __shared__ __align__(16) __hip_bfloat16 b1h[KDIM];       // 4 KB  (perm p)
    __shared__ __align__(16) __hip_bfloat16 evs[BM * 8];     // 4 KB -> 72 KB

    int tid = threadIdx.x, wave = tid >> 6, lane = tid & 63;
    int l31 = lane & 31, half = lane >> 5;
    int bx = blockIdx.x, bm = bx >> 2, bn = bx & 3;

    // --- inline ev for this block's 256 rows (1 sample per thread)
    {
        float K1[8], K2[8];
        #pragma unroll
        for (int i = 0; i < 8; i++) {
            float a = params[i*3+0], b = params[i*3+1], g = params[i*3+2];
            float sa, ca, sb, cb, sg, cg;
            __sincosf(a, &sa, &ca);
            __sincosf(b, &sb, &cb);
            __sincosf(g, &sg, &cg);
            K1[i] = sa*sb*sg + ca*cg;
            K2[i] = cb*sg;
        }
        int n = bm * BM + tid;
        float4 x0 = *(const float4*)(x + (size_t)n*8);
        float4 x1 = *(const float4*)(x + (size_t)n*8 + 4);
        float xs[8] = {x0.x, x0.y, x0.z, x0.w, x1.x, x1.y, x1.z, x1.w};
        float z[8];
        #pragma unroll
        for (int i = 0; i < 8; i++) {
            float s, c;
            __sincosf(xs[i], &s, &c);
            z[i] = c * K1[i] - s * K2[i];
        }
        float evv[8];
        float p = z[0];
        #pragma unroll
        for (int j = 1; j < 8; j++) { p *= z[j]; evv[j] = p; }
        float sfx = z[7];
        #pragma unroll
        for (int j = 6; j >= 1; j--) sfx *= z[j];
        evv[0] = sfx;
        __hip_bfloat16 o[8];
        #pragma unroll
        for (int i = 0; i < 8; i++) o[i] = __float2bfloat16(evv[i]);
        *(bf16x8*)&evs[tid * 8] = *(bf16x8*)o;
    }
    // --- stage W1 (f32->bf16) + b1 (f32->bf16) into LDS, rows permuted by
    //     p(i): within each 32-chunk, swap quads 1<->2 and 5<->6.
    for (int i = tid; i < KDIM; i += 256) {
        int q = (i >> 2) & 3;
        int src = i + ((q == 1) ? 4 : (q == 2) ? -4 : 0);
        float4 wa = *(const float4*)(W1 + (size_t)src * 8);
        float4 wb = *(const float4*)(W1 + (size_t)src * 8 + 4);
        union { u32 u[4]; bf16x8 v; } cw;
        cw.u[0] = pk2(wa.x, wa.y); cw.u[1] = pk2(wa.z, wa.w);
        cw.u[2] = pk2(wb.x, wb.y); cw.u[3] = pk2(wb.z, wb.w);
        *(bf16x8*)&W1s[i * 8] = cw.v;
        b1h[i] = __float2bfloat16(b1[src]);
    }

    // W2 f32 pointers: wave stages frags f = wave*2+i (i=0,1); f = ni*2+t;
    // lane reads row (bn*BN + ni*32 + l31), cols k0 + t*16 + half*8 .. +8
    const float* gW0;
    const float* gW1;
    {
        int f0 = wave * 2 + 0, f1 = wave * 2 + 1;
        gW0 = W2 + (size_t)(bn*BN + (f0 >> 1)*32 + l31) * KDIM + (f0 & 1)*16 + half*8;
        gW1 = W2 + (size_t)(bn*BN + (f1 >> 1)*32 + l31) * KDIM + (f1 & 1)*16 + half*8;
    }
    float4 rA0, rA1, rB0, rB1;   // staged tile (single set, 16 VGPR)

#define LOADW2() do {                                                         \
        rA0 = *(const float4*)gW0; rA1 = *(const float4*)(gW0 + 4);           \
        rB0 = *(const float4*)gW1; rB1 = *(const float4*)(gW1 + 4);           \
        gW0 += 32; gW1 += 32;                                                 \
    } while (0)

#define CVTWRITE(BUFIDX) do {                                                 \
        union { u32 u[4]; bf16x8 v; } c0, c1;                                 \
        c0.u[0] = pk2(rA0.x, rA0.y); c0.u[1] = pk2(rA0.z, rA0.w);             \
        c0.u[2] = pk2(rA1.x, rA1.y); c0.u[3] = pk2(rA1.z, rA1.w);             \
        c1.u[0] = pk2(rB0.x, rB0.y); c1.u[1] = pk2(rB0.z, rB0.w);             \
        c1.u[2] = pk2(rB1.x, rB1.y); c1.u[3] = pk2(rB1.z, rB1.w);             \
        *(bf16x8*)&Bs[BUFIDX][(wave*2 + 0) * 512 + lane * 8] = c0.v;          \
        *(bf16x8*)&Bs[BUFIDX][(wave*2 + 1) * 512 + lane * 8] = c1.v;          \
    } while (0)

    // prologue: tile 0 load+write, tile 1 issue (drained by __syncthreads)
    LOADW2();
    asm volatile("s_waitcnt vmcnt(0)" ::: "memory");
    CVTWRITE(0);
    LOADW2();
    __syncthreads();   // evs/W1s/b1h + Bs[0] visible; tile1 regs loaded

    // GEMM1 B-operands: half0 = the wave's two 32-row ev groups; half1 = unit
    bf16x8 evB0, evB1;
    if (half == 0) {
        evB0 = *(bf16x8*)&evs[(wave * 64 +      l31) * 8];
        evB1 = *(bf16x8*)&evs[(wave * 64 + 32 + l31) * 8];
    } else {
        evB0 = (bf16x8){};
        evB0[0] = (__bf16)1.0f;
        evB1 = evB0;
    }
    const f32x16 z16 = {};   // loop-invariant zero C-in for GEMM1

    f32x16 acc[8] = {};   // [rg*4 + ni]

#define COMPUTE_AF(K0, A00, A01, A10, A11) do {                               \
        bf16x8 w1f;                                                           \
        if (half == 0) {                                                      \
            w1f = *(const bf16x8*)&W1s[((K0) + l31) * 8];                     \
        } else {                                                              \
            w1f = (bf16x8){};                                                 \
            w1f[0] = *(const __bf16*)&b1h[(K0) + l31];                        \
        }                                                                     \
        f32x16 h0 = __builtin_amdgcn_mfma_f32_32x32x16_bf16(w1f, evB0, z16, 0, 0, 0); \
        h_to_af(h0, A00, A01);                                                \
        f32x16 h1 = __builtin_amdgcn_mfma_f32_32x32x16_bf16(w1f, evB1, z16, 0, 0, 0); \
        h_to_af(h1, A10, A11);                                                \
    } while (0)

#define GEMM2_STEP(CB, A00, A01, A10, A11) do {                               \
        __builtin_amdgcn_s_setprio(1);                                        \
        _Pragma("unroll")                                                     \
        for (int ni = 0; ni < 4; ni++) {                                      \
            bf16x8 bf0 = *(bf16x8*)&Bs[CB][(ni*2 + 0) * 512 + lane * 8];      \
            acc[ni]     = __builtin_amdgcn_mfma_f32_32x32x16_bf16(A00, bf0, acc[ni],     0, 0, 0); \
            acc[4 + ni] = __builtin_amdgcn_mfma_f32_32x32x16_bf16(A10, bf0, acc[4 + ni], 0, 0, 0); \
            bf16x8 bf1 = *(bf16x8*)&Bs[CB][(ni*2 + 1) * 512 + lane * 8];      \
            acc[ni]     = __builtin_amdgcn_mfma_f32_32x32x16_bf16(A01, bf1, acc[ni],     0, 0, 0); \
            acc[4 + ni] = __builtin_amdgcn_mfma_f32_32x32x16_bf16(A11, bf1, acc[4 + ni], 0, 0, 0); \
        }                                                                     \
        __builtin_amdgcn_s_setprio(0);                                        \
    } while (0)

    // iter T: COMPUTE_AF(T) -> cvt+write tile T+1 -> issue tile T+2 ->
    // lgkm+barrier -> GEMM2(T). Compiler auto-waits vmcnt for the cvt reads.
#define K_ITER(T, BUF, DO_CVT, DO_ISSUE) do {                                 \
        COMPUTE_AF((T) * 32, aA00, aA01, aA10, aA11);                         \
        if (DO_CVT)   CVTWRITE(((BUF) + 1) & 3);                              \
        if (DO_ISSUE) LOADW2();                                               \
        if (DO_CVT) {                                                         \
            asm volatile("s_waitcnt lgkmcnt(0)" ::: "memory");                \
            __builtin_amdgcn_s_barrier();                                     \
        }                                                                     \
        GEMM2_STEP(BUF, aA00, aA01, aA10, aA11);                              \
    } while (0)

    bf16x8 aA00, aA01, aA10, aA11;

    for (int it0 = 0; it0 < NITER - 4; it0 += 4) {
        K_ITER(it0 + 0, 0, 1, 1);
        K_ITER(it0 + 1, 1, 1, 1);
        K_ITER(it0 + 2, 2, 1, 1);
        K_ITER(it0 + 3, 3, 1, 1);
    }
    K_ITER(NITER - 4, 0, 1, 1);   // issues tile 62
    K_ITER(NITER - 3, 1, 1, 1);   // issues tile 63
    K_ITER(NITER - 2, 2, 1, 0);   // cvt+write tile 63
    K_ITER(NITER - 1, 3, 0, 0);   // plain GEMM2 on Bs[3]

#undef K_ITER
#undef COMPUTE_AF
#undef GEMM2_STEP
#undef CVTWRITE
#undef LOADW2

    // epilogue: 32x32 C/D layout: col = lane&31, row = (r&3)+8*(r>>2)+4*half
    #pragma unroll
    for (int rg = 0; rg < 2; rg++) {
        int rbase = bm*BM + wave*64 + rg*32 + 4*half;
        #pragma unroll
        for (int ni = 0; ni < 4; ni++) {
            int col = bn*BN + ni*32 + l31;
            float bias = b2[col];
            #pragma unroll
            for (int r = 0; r < 16; r++) {
                int row = rbase + (r & 3) + 8 * (r >> 2);
                C[(size_t)row * EMB + col] = acc[rg*4 + ni][r] + bias;
            }
        }
    }
}

extern "C" void kernel_launch(void* const* d_in, const int* in_sizes, int n_in,
                              void* d_out, int out_size, void* d_ws, size_t ws_size,
                              hipStream_t stream) {
    const float* x      = (const float*)d_in[0];  // [16,2048,8]
    const float* params = (const float*)d_in[1];  // [8,3]
    const float* W1     = (const float*)d_in[2];  // [2048,8]
    const float* b1     = (const float*)d_in[3];  // [2048]
    const float* W2     = (const float*)d_in[4];  // [512,2048]
    const float* b2     = (const float*)d_in[5];  // [512]
    float* out = (float*)d_out;                   // [32768,512]

    // single launch: all f32->bf16 conversion fused into k_gemm
    k_gemm<<<(NS/BM) * (EMB/BN), 256, 0, stream>>>(x, params, W1, b1, W2, b2, out);
}

// Round 9
// 149.305 us; speedup vs baseline: 1.0438x; 1.0438x over previous
//
#include <hip/hip_runtime.h>
#include <hip/hip_bf16.h>

#define NS 32768          // B*S samples
#define EMB 512
#define KDIM 2048
#define BM 256
#define BN 128
#define NITER (KDIM / 32)   // 64

typedef float f32x16 __attribute__((ext_vector_type(16)));
typedef __bf16 bf16x8 __attribute__((ext_vector_type(8)));
typedef __bf16 bf16x2 __attribute__((ext_vector_type(2)));
typedef unsigned int u32;
typedef const __attribute__((address_space(1))) u32* gptr_t;
typedef __attribute__((address_space(3))) u32* lptr_t;

__device__ __forceinline__ void gload_lds16(const void* g, void* l) {
    __builtin_amdgcn_global_load_lds((gptr_t)g, (lptr_t)l, 16, 0, 0);
}

// pack two relu'd floats into one u32 of 2 bf16 (v_cvt_pk_bf16_f32)
__device__ __forceinline__ u32 pkrelu(float lo, float hi) {
    union { bf16x2 h; u32 u; } c;
    c.h[0] = (__bf16)fmaxf(lo, 0.f);
    c.h[1] = (__bf16)fmaxf(hi, 0.f);
    return c.u;
}

__device__ __forceinline__ bf16x8 mk_af(u32 a, u32 b, u32 c, u32 d) {
    union { u32 u[4]; bf16x8 v; } t;
    t.u[0] = a; t.u[1] = b; t.u[2] = c; t.u[3] = d;
    return t.v;
}

// GEMM1 C/D regs -> two GEMM2 A-fragments. With the hidden-index
// pre-permutation (W1/b1 rows permuted by p(i) at stage time, verified r5-7),
// D reg r at (l31,half) holds H_orig[k0 + t*16 + half*8 + j] in A-frag
// order: af0 = regs 0..7 pairwise-packed, af1 = regs 8..15. No cross-lane.
__device__ __forceinline__ void h_to_af(const f32x16 h, bf16x8& af0, bf16x8& af1) {
    af0 = mk_af(pkrelu(h[0], h[1]),  pkrelu(h[2], h[3]),
                pkrelu(h[4], h[5]),  pkrelu(h[6], h[7]));
    af1 = mk_af(pkrelu(h[8], h[9]),  pkrelu(h[10], h[11]),
                pkrelu(h[12], h[13]), pkrelu(h[14], h[15]));
}

// ---- prep: W2 -> bf16 (1024 blocks); W1 -> bf16 (16 blocks) ----
__global__ __launch_bounds__(256) void k_prep(const float* __restrict__ W2,
                                              const float* __restrict__ W1,
                                              __hip_bfloat16* __restrict__ W2b,
                                              __hip_bfloat16* __restrict__ W1bg) {
    int t = threadIdx.x;
    if (blockIdx.x < 1024) {
        int i = (blockIdx.x * 256 + t) * 4;
        float4 v = *(const float4*)(W2 + i);
        __hip_bfloat16 o[4];
        o[0] = __float2bfloat16(v.x); o[1] = __float2bfloat16(v.y);
        o[2] = __float2bfloat16(v.z); o[3] = __float2bfloat16(v.w);
        *(ulong1*)(W2b + i) = *(ulong1*)o;
    } else {
        int j = (blockIdx.x - 1024) * 1024 + t * 4;   // 16 blocks x 1024
        float4 w = *(const float4*)(W1 + j);
        __hip_bfloat16 p[4];
        p[0] = __float2bfloat16(w.x); p[1] = __float2bfloat16(w.y);
        p[2] = __float2bfloat16(w.z); p[3] = __float2bfloat16(w.w);
        *(ulong1*)(W1bg + j) = *(ulong1*)p;
    }
}

// ---- fused: C[256,128-tile] = relu(ev @ W1^T + b1) @ W2b^T + b2 ----
// Round-7 structure (best verified: quad-buffer Bs, prefetch distance 2,
// ONE raw s_barrier/iter with counted vmcnt(4), GEMM1-on-MFMA with b1 folded,
// hidden pre-permutation, reuse-2 GEMM2) + restored one-iter-ahead AF:
//  * COMPUTE_AF(T+1) runs BEFORE the barrier at iter T (ping-pong af sets),
//    so the serial MFMA1 -> 16x cvt_pk -> af chain is off the post-barrier
//    critical path; GEMM2(T) issues from ready registers immediately.
__global__ __launch_bounds__(256, 2) void k_gemm(
        const float* __restrict__ x,       // [NS, 8]
        const float* __restrict__ params,  // [8, 3]
        const __hip_bfloat16* __restrict__ W1bg,  // [2048, 8] bf16
        const float* __restrict__ b1,      // [2048]
        const __hip_bfloat16* __restrict__ W2b,   // [512, 2048] bf16
        const float* __restrict__ b2,      // [512]
        float* __restrict__ C) {           // [NS, 512]
    __shared__ __hip_bfloat16 Bs[4][8 * 512];  // quad-buffered, 4 x 8 KB
    __shared__ __hip_bfloat16 W1s[KDIM * 8];   // 32 KB (rows permuted by p)
    __shared__ __hip_bfloat16 b1h[KDIM];       // 4 KB  (permuted by p)
    __shared__ __hip_bfloat16 evs[BM * 8];     // 4 KB  -> total 72 KB, 2 blk/CU

    int tid = threadIdx.x, wave = tid >> 6, lane = tid & 63;
    int l31 = lane & 31, half = lane >> 5;
    int bx = blockIdx.x, bm = bx >> 2, bn = bx & 3;

    // --- inline ev for this block's 256 rows (1 sample per thread)
    {
        float K1[8], K2[8];
        #pragma unroll
        for (int i = 0; i < 8; i++) {
            float a = params[i*3+0], b = params[i*3+1], g = params[i*3+2];
            float sa, ca, sb, cb, sg, cg;
            __sincosf(a, &sa, &ca);
            __sincosf(b, &sb, &cb);
            __sincosf(g, &sg, &cg);
            K1[i] = sa*sb*sg + ca*cg;
            K2[i] = cb*sg;
        }
        int n = bm * BM + tid;
        float4 x0 = *(const float4*)(x + (size_t)n*8);
        float4 x1 = *(const float4*)(x + (size_t)n*8 + 4);
        float xs[8] = {x0.x, x0.y, x0.z, x0.w, x1.x, x1.y, x1.z, x1.w};
        float z[8];
        #pragma unroll
        for (int i = 0; i < 8; i++) {
            float s, c;
            __sincosf(xs[i], &s, &c);
            z[i] = c * K1[i] - s * K2[i];
        }
        float evv[8];
        float p = z[0];
        #pragma unroll
        for (int j = 1; j < 8; j++) { p *= z[j]; evv[j] = p; }
        float sfx = z[7];
        #pragma unroll
        for (int j = 6; j >= 1; j--) sfx *= z[j];
        evv[0] = sfx;
        __hip_bfloat16 o[8];
        #pragma unroll
        for (int i = 0; i < 8; i++) o[i] = __float2bfloat16(evv[i]);
        *(bf16x8*)&evs[tid * 8] = *(bf16x8*)o;
    }
    // --- stage W1 (bf16) + b1 (bf16) into LDS, rows permuted by p(i):
    //     within each 32-chunk, swap quads 1<->2 and 5<->6.
    for (int i = tid; i < KDIM; i += 256) {
        int q = (i >> 2) & 3;
        int src = i + ((q == 1) ? 4 : (q == 2) ? -4 : 0);
        *(bf16x8*)&W1s[i * 8] = *(const bf16x8*)(W1bg + (size_t)src * 8);
        b1h[i] = __float2bfloat16(b1[src]);
    }

    // B staging: wave stages frags f = wave*2, wave*2+1  (8 frags = 4 ni x 2 t)
    const __hip_bfloat16* gBp[2];
    #pragma unroll
    for (int i = 0; i < 2; i++) {
        int f = wave * 2 + i, ni = f >> 1, t = f & 1;
        gBp[i] = W2b + (size_t)(bn*BN + ni*32 + l31) * KDIM + t*16 + half*8;
    }
    // prologue: stage tiles 0 and 1 -> Bs[0], Bs[1]
    #pragma unroll
    for (int b = 0; b < 2; b++) {
        #pragma unroll
        for (int i = 0; i < 2; i++) {
            gload_lds16(gBp[i], &Bs[b][(wave*2 + i) * 512]);
            gBp[i] += 32;
        }
    }

    __syncthreads();   // evs/W1s/b1h written; tiles 0,1 staged+drained

    // GEMM1 B-operands: half0 = the wave's two 32-row ev groups; half1 = unit
    bf16x8 evB0, evB1;
    if (half == 0) {
        evB0 = *(bf16x8*)&evs[(wave * 64 +      l31) * 8];
        evB1 = *(bf16x8*)&evs[(wave * 64 + 32 + l31) * 8];
    } else {
        evB0 = (bf16x8){};
        evB0[0] = (__bf16)1.0f;
        evB1 = evB0;
    }
    const f32x16 z16 = {};   // loop-invariant zero C-in for GEMM1

    f32x16 acc[8] = {};   // [rg*4 + ni]

#define COMPUTE_AF(K0, A00, A01, A10, A11) do {                               \
        bf16x8 w1f;                                                           \
        if (half == 0) {                                                      \
            w1f = *(const bf16x8*)&W1s[((K0) + l31) * 8];                     \
        } else {                                                              \
            w1f = (bf16x8){};                                                 \
            w1f[0] = *(const __bf16*)&b1h[(K0) + l31];                        \
        }                                                                     \
        f32x16 h0 = __builtin_amdgcn_mfma_f32_32x32x16_bf16(w1f, evB0, z16, 0, 0, 0); \
        h_to_af(h0, A00, A01);                                                \
        f32x16 h1 = __builtin_amdgcn_mfma_f32_32x32x16_bf16(w1f, evB1, z16, 0, 0, 0); \
        h_to_af(h1, A10, A11);                                                \
    } while (0)

#define GEMM2_STEP(CB, A00, A01, A10, A11) do {                               \
        __builtin_amdgcn_s_setprio(1);                                        \
        _Pragma("unroll")                                                     \
        for (int ni = 0; ni < 4; ni++) {                                      \
            bf16x8 bf0 = *(bf16x8*)&Bs[CB][(ni*2 + 0) * 512 + lane * 8];      \
            acc[ni]     = __builtin_amdgcn_mfma_f32_32x32x16_bf16(A00, bf0, acc[ni],     0, 0, 0); \
            acc[4 + ni] = __builtin_amdgcn_mfma_f32_32x32x16_bf16(A10, bf0, acc[4 + ni], 0, 0, 0); \
            bf16x8 bf1 = *(bf16x8*)&Bs[CB][(ni*2 + 1) * 512 + lane * 8];      \
            acc[ni]     = __builtin_amdgcn_mfma_f32_32x32x16_bf16(A01, bf1, acc[ni],     0, 0, 0); \
            acc[4 + ni] = __builtin_amdgcn_mfma_f32_32x32x16_bf16(A11, bf1, acc[4 + ni], 0, 0, 0); \
        }                                                                     \
        __builtin_amdgcn_s_setprio(0);                                        \
    } while (0)

    // iter T: stage tile T+2, COMPUTE_AF(T+1) into NEXT set, counted-vmcnt
    // wait, raw barrier, GEMM2(T) on CURRENT set. VMC is a string literal.
#define K_ITER(T, BUF, DO_STAGE, VMC, DO_AF, C00,C01,C10,C11, N00,N01,N10,N11) do { \
        if (DO_STAGE) {                                                       \
            gload_lds16(gBp[0], &Bs[((BUF) + 2) & 3][(wave*2 + 0) * 512]);    \
            gload_lds16(gBp[1], &Bs[((BUF) + 2) & 3][(wave*2 + 1) * 512]);    \
            gBp[0] += 32; gBp[1] += 32;                                       \
        }                                                                     \
        if (DO_AF) COMPUTE_AF(((T) + 1) * 32, N00, N01, N10, N11);            \
        asm volatile("s_waitcnt vmcnt(" VMC ")" ::: "memory");                \
        __builtin_amdgcn_s_barrier();                                         \
        GEMM2_STEP(BUF, C00, C01, C10, C11);                                  \
    } while (0)

    bf16x8 aA00, aA01, aA10, aA11;   // af set for even iters
    bf16x8 aB00, aB01, aB10, aB11;   // af set for odd iters
    COMPUTE_AF(0, aA00, aA01, aA10, aA11);

    for (int it0 = 0; it0 < NITER - 4; it0 += 4) {
        K_ITER(it0 + 0, 0, 1, "4", 1, aA00,aA01,aA10,aA11, aB00,aB01,aB10,aB11);
        K_ITER(it0 + 1, 1, 1, "4", 1, aB00,aB01,aB10,aB11, aA00,aA01,aA10,aA11);
        K_ITER(it0 + 2, 2, 1, "4", 1, aA00,aA01,aA10,aA11, aB00,aB01,aB10,aB11);
        K_ITER(it0 + 3, 3, 1, "4", 1, aB00,aB01,aB10,aB11, aA00,aA01,aA10,aA11);
    }
    // final group: t = 60..63 (stages tiles 62, 63; drains 2, 0; last has no AF)
    K_ITER(NITER - 4, 0, 1, "4", 1, aA00,aA01,aA10,aA11, aB00,aB01,aB10,aB11);
    K_ITER(NITER - 3, 1, 1, "4", 1, aB00,aB01,aB10,aB11, aA00,aA01,aA10,aA11);
    K_ITER(NITER - 2, 2, 0, "2", 1, aA00,aA01,aA10,aA11, aB00,aB01,aB10,aB11);
    K_ITER(NITER - 1, 3, 0, "0", 0, aB00,aB01,aB10,aB11, aA00,aA01,aA10,aA11);

#undef K_ITER
#undef COMPUTE_AF
#undef GEMM2_STEP

    // epilogue: 32x32 C/D layout: col = lane&31, row = (r&3)+8*(r>>2)+4*half
    #pragma unroll
    for (int rg = 0; rg < 2; rg++) {
        int rbase = bm*BM + wave*64 + rg*32 + 4*half;
        #pragma unroll
        for (int ni = 0; ni < 4; ni++) {
            int col = bn*BN + ni*32 + l31;
            float bias = b2[col];
            #pragma unroll
            for (int r = 0; r < 16; r++) {
                int row = rbase + (r & 3) + 8 * (r >> 2);
                C[(size_t)row * EMB + col] = acc[rg*4 + ni][r] + bias;
            }
        }
    }
}

extern "C" void kernel_launch(void* const* d_in, const int* in_sizes, int n_in,
                              void* d_out, int out_size, void* d_ws, size_t ws_size,
                              hipStream_t stream) {
    const float* x      = (const float*)d_in[0];  // [16,2048,8]
    const float* params = (const float*)d_in[1];  // [8,3]
    const float* W1     = (const float*)d_in[2];  // [2048,8]
    const float* b1     = (const float*)d_in[3];  // [2048]
    const float* W2     = (const float*)d_in[4];  // [512,2048]
    const float* b2     = (const float*)d_in[5];  // [512]
    float* out = (float*)d_out;                   // [32768,512]

    char* ws = (char*)d_ws;
    __hip_bfloat16* W2b  = (__hip_bfloat16*)ws;              // 2 MB
    __hip_bfloat16* W1bg = (__hip_bfloat16*)(ws + 2097152);  // 32 KB

    k_prep<<<1040, 256, 0, stream>>>(W2, W1, W2b, W1bg);
    k_gemm<<<(NS/BM) * (EMB/BN), 256, 0, stream>>>(x, params, W1bg, b1, W2b, b2, out);
}